// Round 14
// baseline (37.601 us; speedup 1.0000x reference)
//
#include <hip/hip_runtime.h>

// CenterNeighAtt on MI355X. E=512, F=256, R=4.
//
// Exact math simplifications (validated R1-R13, absmax ~5e-4 vs 2.3e-3 threshold):
//  * alpha = softmax_j(sum_i scores[i,j]) is uniform 1/E: sum_i attention[i,j,f]==1,
//    so column sums of scores are constant in j. lin_w/lin_b are dead inputs.
//  * No max-subtraction in softmaxes: logits bounded (~20), exp far below f32 overflow.
//
// Structure lessons (measured):
//  * Cross-grid sync / __threadfence in-dispatch: toxic (R3/R5/R6/R7). Kernel
//    boundaries + plain stores ONLY. Per-dispatch gap ~3us.
//  * f-split + 2 blk/CU + 8 waves/SIMD + 3 dispatches = best structure (R13, 37.4us).
//  * Interiors VALU-ISSUE-bound incl. compiler overhead (R7: 11us busy vs 4.7us
//    hand-count; traffic varied 4x with no interior change R11-R13).
//  * Rule #20: only tiny fully-unrolled per-thread arrays. No hand VOP3P asm (R10).
//
// R14 = R13 with 4 rows x 2-f (f2) per thread: 1 dwordx2 + 1 ds_read_b128 per
// 8 elements, homogeneous f2 arithmetic for compiler pk-packing. g stored SoA.

typedef float f2 __attribute__((ext_vector_type(2)));
typedef float f4 __attribute__((ext_vector_type(4)));

#define EE 512
#define FF 256
#define RRR 4
#define LOG2E 1.44269504088896340736f
#define RPB 4      // rows per block
#define NT 32      // teams
#define CH 16      // chunk length (512/32)
#define FPB 32     // f-pairs per block (64 f)

// --- kA: s[i,:] = softmax_j(sum_r adj[r,i,:]); alpha -----------------------
__global__ __launch_bounds__(256) void kA(const float* __restrict__ adj,
                                          float* __restrict__ s,
                                          float* __restrict__ out) {
    const int i = blockIdx.x;
    const int t = threadIdx.x;
    if (i == 0) {   // alpha: softmax of a constant vector = uniform 1/E
        out[EE * FF + t]       = 1.0f / EE;
        out[EE * FF + 256 + t] = 1.0f / EE;
    }
    const float* base = adj + (size_t)i * EE;
    float t0 = 0.f, t1 = 0.f;
#pragma unroll
    for (int r = 0; r < RRR; ++r) {
        t0 += base[(size_t)r * EE * EE + t];
        t1 += base[(size_t)r * EE * EE + t + 256];
    }
    const float e0 = __expf(t0);
    const float e1 = __expf(t1);
    __shared__ float red[256];
    red[t] = e0 + e1;
    __syncthreads();
    for (int off = 128; off > 0; off >>= 1) {
        if (t < off) red[t] += red[t + off];
        __syncthreads();
    }
    const float inv = 1.0f / red[0];
    s[(size_t)i * EE + t]       = e0 * inv;
    s[(size_t)i * EE + t + 256] = e1 * inv;
}

// --- kB: Z[j,f] = sum_i exp2(lrelu(s[i,j]*h[i,f]*h[j,f])*log2e);
//         g[j,f] = h[j,f] * rcp(Z) -----------------------------------------
__global__ __launch_bounds__(1024, 8) void kB(const float* __restrict__ h,
                                              const float* __restrict__ s,
                                              float* __restrict__ g) {
    const int tid  = threadIdx.x;
    const int fp   = tid & (FPB - 1);           // 0..31 f-pair
    const int team = tid >> 5;                  // 0..31
    const int j0   = blockIdx.x * RPB;
    const int f0   = blockIdx.y * (2 * FPB) + fp * 2;
    __shared__ __align__(16) float sl[EE * RPB];   // 8 KB: sl[i*4+r] = s[i][j0+r]
    __shared__ f2 ps[NT * RPB * FPB];              // 32 KB
#pragma unroll
    for (int p = 0; p < 2; ++p) {
        const int idx = tid + p * 1024;
        sl[idx] = s[(size_t)(idx >> 2) * EE + j0 + (idx & 3)];
    }
    __syncthreads();
    const f2 hj0 = *(const f2*)(h + (size_t)(j0 + 0) * FF + f0) * LOG2E;
    const f2 hj1 = *(const f2*)(h + (size_t)(j0 + 1) * FF + f0) * LOG2E;
    const f2 hj2 = *(const f2*)(h + (size_t)(j0 + 2) * FF + f0) * LOG2E;
    const f2 hj3 = *(const f2*)(h + (size_t)(j0 + 3) * FF + f0) * LOG2E;
    f2 Z0 = {0.f, 0.f}, Z1 = {0.f, 0.f}, Z2 = {0.f, 0.f}, Z3 = {0.f, 0.f};
    const float* hp = h + (size_t)(team * CH) * FF + f0;
    const f4* spv = (const f4*)(sl + team * CH * RPB);
#pragma unroll 2
    for (int ii = 0; ii < CH; ++ii) {
        const f2 hif = *(const f2*)(hp + (size_t)ii * FF);   // serves 8 elements
        const f4 sv  = spv[ii];                              // b128 broadcast
        {   const f2 y = hj0 * hif * sv.x;
            const f2 m = __builtin_elementwise_max(y, y * 0.2f);
            Z0 += (f2){__builtin_amdgcn_exp2f(m.x), __builtin_amdgcn_exp2f(m.y)}; }
        {   const f2 y = hj1 * hif * sv.y;
            const f2 m = __builtin_elementwise_max(y, y * 0.2f);
            Z1 += (f2){__builtin_amdgcn_exp2f(m.x), __builtin_amdgcn_exp2f(m.y)}; }
        {   const f2 y = hj2 * hif * sv.z;
            const f2 m = __builtin_elementwise_max(y, y * 0.2f);
            Z2 += (f2){__builtin_amdgcn_exp2f(m.x), __builtin_amdgcn_exp2f(m.y)}; }
        {   const f2 y = hj3 * hif * sv.w;
            const f2 m = __builtin_elementwise_max(y, y * 0.2f);
            Z3 += (f2){__builtin_amdgcn_exp2f(m.x), __builtin_amdgcn_exp2f(m.y)}; }
    }
    ps[(team * RPB + 0) * FPB + fp] = Z0;
    ps[(team * RPB + 1) * FPB + fp] = Z1;
    ps[(team * RPB + 2) * FPB + fp] = Z2;
    ps[(team * RPB + 3) * FPB + fp] = Z3;
    __syncthreads();
    if (tid < RPB * FPB) {                       // 128 threads finish 256 outputs
        const int r = tid >> 5, fq = tid & (FPB - 1);
        f2 Zt = {0.f, 0.f};
#pragma unroll
        for (int t = 0; t < NT; ++t) Zt += ps[(t * RPB + r) * FPB + fq];
        const size_t o = (size_t)(j0 + r) * FF + blockIdx.y * (2 * FPB) + fq * 2;
        const f2 hv = *(const f2*)(h + o);
        *(f2*)(g + o) = (f2){hv.x * __builtin_amdgcn_rcpf(Zt.x),
                             hv.y * __builtin_amdgcn_rcpf(Zt.y)};
    }
}

// --- kC: out[i,f] = elu(sum_j g[j,f]*exp2(lrelu(s[i,j]*h[i,f]*h[j,f])*log2e))
__global__ __launch_bounds__(1024, 8) void kC(const float* __restrict__ h,
                                              const float* __restrict__ s,
                                              const float* __restrict__ g,
                                              float* __restrict__ out) {
    const int tid  = threadIdx.x;
    const int fp   = tid & (FPB - 1);
    const int team = tid >> 5;
    const int i0   = blockIdx.x * RPB;
    const int f0   = blockIdx.y * (2 * FPB) + fp * 2;
    __shared__ __align__(16) float sl[EE * RPB];   // sl[j*4+r] = s[i0+r][j]
    __shared__ f2 ps[NT * RPB * FPB];
#pragma unroll
    for (int p = 0; p < 2; ++p) {
        const int idx = tid + p * 1024;
        sl[idx] = s[(size_t)(i0 + (idx & 3)) * EE + (idx >> 2)];
    }
    __syncthreads();
    const f2 hl0 = *(const f2*)(h + (size_t)(i0 + 0) * FF + f0) * LOG2E;
    const f2 hl1 = *(const f2*)(h + (size_t)(i0 + 1) * FF + f0) * LOG2E;
    const f2 hl2 = *(const f2*)(h + (size_t)(i0 + 2) * FF + f0) * LOG2E;
    const f2 hl3 = *(const f2*)(h + (size_t)(i0 + 3) * FF + f0) * LOG2E;
    f2 a0 = {0.f, 0.f}, a1 = {0.f, 0.f}, a2 = {0.f, 0.f}, a3 = {0.f, 0.f};
    const float* hp = h + (size_t)(team * CH) * FF + f0;
    const float* gp = g + (size_t)(team * CH) * FF + f0;
    const f4* spv = (const f4*)(sl + team * CH * RPB);
#pragma unroll 2
    for (int jj = 0; jj < CH; ++jj) {
        const f2 hjf = *(const f2*)(hp + (size_t)jj * FF);
        const f2 gj  = *(const f2*)(gp + (size_t)jj * FF);
        const f4 sv  = spv[jj];                              // b128 broadcast
        {   const f2 y = hl0 * hjf * sv.x;
            const f2 m = __builtin_elementwise_max(y, y * 0.2f);
            a0 += (f2){__builtin_amdgcn_exp2f(m.x), __builtin_amdgcn_exp2f(m.y)} * gj; }
        {   const f2 y = hl1 * hjf * sv.y;
            const f2 m = __builtin_elementwise_max(y, y * 0.2f);
            a1 += (f2){__builtin_amdgcn_exp2f(m.x), __builtin_amdgcn_exp2f(m.y)} * gj; }
        {   const f2 y = hl2 * hjf * sv.z;
            const f2 m = __builtin_elementwise_max(y, y * 0.2f);
            a2 += (f2){__builtin_amdgcn_exp2f(m.x), __builtin_amdgcn_exp2f(m.y)} * gj; }
        {   const f2 y = hl3 * hjf * sv.w;
            const f2 m = __builtin_elementwise_max(y, y * 0.2f);
            a3 += (f2){__builtin_amdgcn_exp2f(m.x), __builtin_amdgcn_exp2f(m.y)} * gj; }
    }
    ps[(team * RPB + 0) * FPB + fp] = a0;
    ps[(team * RPB + 1) * FPB + fp] = a1;
    ps[(team * RPB + 2) * FPB + fp] = a2;
    ps[(team * RPB + 3) * FPB + fp] = a3;
    __syncthreads();
    if (tid < RPB * FPB) {
        const int r = tid >> 5, fq = tid & (FPB - 1);
        f2 a = {0.f, 0.f};
#pragma unroll
        for (int t = 0; t < NT; ++t) a += ps[(t * RPB + r) * FPB + fq];
        const f2 res = {(a.x > 0.f) ? a.x : (__expf(a.x) - 1.0f),
                        (a.y > 0.f) ? a.y : (__expf(a.y) - 1.0f)};
        *(f2*)(out + (size_t)(i0 + r) * FF + blockIdx.y * (2 * FPB) + fq * 2) = res;
    }
}

extern "C" void kernel_launch(void* const* d_in, const int* in_sizes, int n_in,
                              void* d_out, int out_size, void* d_ws, size_t ws_size,
                              hipStream_t stream) {
    const float* h   = (const float*)d_in[0];  // [E,F]
    const float* adj = (const float*)d_in[1];  // [R,E,E]
    // lin_w / lin_b mathematically dead (alpha uniform).

    float* s   = (float*)d_ws;                 // 1 MB
    float* g   = s + (size_t)EE * EE;          // 512 KB (total 1.5 MB)
    float* out = (float*)d_out;

    kA<<<EE, 256, 0, stream>>>(adj, s, out);
    kB<<<dim3(EE / RPB, FF / (2 * FPB)), 1024, 0, stream>>>(h, s, g);
    kC<<<dim3(EE / RPB, FF / (2 * FPB)), 1024, 0, stream>>>(h, s, g, out);
}